// Round 20
// baseline (207.998 us; speedup 1.0000x reference)
//
#include <hip/hip_runtime.h>
#include <hip/hip_bf16.h>
#include <cstdint>
#include <cstddef>

#define HIDDEN   2048
#define NH       16
#define NKV      4
#define HD       128
#define SEQ      2048
#define BATCH    2
#define NTOK     (BATCH*SEQ)      // 4096
#define QKV_LD   3072             // Q(2048) | K(512) | V(512)
#define KOFF     2048
#define VOFF     2560
#define SM_SCALE 0.08838834764831845f   // 1/sqrt(128)
#define LOG2E    1.4426950408889634f

typedef __attribute__((ext_vector_type(8)))  short bf16x8;
typedef __attribute__((ext_vector_type(4)))  float f32x4v;
typedef __attribute__((ext_vector_type(16))) float f32x16;
typedef unsigned short ushort_t;

__device__ __forceinline__ unsigned short f2bf(float f) {
  return __builtin_bit_cast(unsigned short, __float2bfloat16(f));
}
__device__ __forceinline__ float bf2f(ushort_t u) {
  return __builtin_bit_cast(float, (unsigned)u << 16);
}
__device__ __forceinline__ unsigned pack2(float a, float b) {
  return (unsigned)f2bf(a) | ((unsigned)f2bf(b) << 16);
}

// async global->LDS, 16B/lane; LDS dest lane-linear, swizzle realized on the GLOBAL src.
__device__ __forceinline__ void gload16(const void* g, void* l) {
  __builtin_amdgcn_global_load_lds(
      (const __attribute__((address_space(1))) unsigned int*)g,
      (__attribute__((address_space(3))) unsigned int*)l, 16, 0, 0);
}

// ---------------- conversion kernels ----------------
// fp32 -> bf16 at copy roofline: 2048 blocks, 16 elems (64B in / 32B out) per thread
__global__ __launch_bounds__(256) void conv_f2b(
    const float* __restrict__ in, ushort_t* __restrict__ out, int n16)
{
  const int i = blockIdx.x*256 + threadIdx.x;
  if (i >= n16) return;
  const float4* ip = (const float4*)in + 4*i;
  const float4 a = ip[0], b = ip[1], c = ip[2], d = ip[3];
  uint4 r0, r1;
  r0.x = pack2(a.x, a.y); r0.y = pack2(a.z, a.w);
  r0.z = pack2(b.x, b.y); r0.w = pack2(b.z, b.w);
  r1.x = pack2(c.x, c.y); r1.y = pack2(c.z, c.w);
  r1.z = pack2(d.x, d.y); r1.w = pack2(d.z, d.w);
  ((uint4*)out)[2*i]   = r0;
  ((uint4*)out)[2*i+1] = r1;
}

// Fused Wq|Wk|Wv transpose: W[K=2048][N] fp32 -> Wt[N][2048] bf16.
__global__ __launch_bounds__(256) void transpose_qkv_f2b(
    const float* __restrict__ Wq, const float* __restrict__ Wk,
    const float* __restrict__ Wv, ushort_t* __restrict__ Wt)
{
  __shared__ float tile[32][33];
  const int xb = blockIdx.x;
  const float* W; ushort_t* dst; int N, nt;
  if (xb < 64)      { W = Wq; dst = Wt;                         N = 2048; nt = xb; }
  else if (xb < 80) { W = Wk; dst = Wt + (size_t)2048*2048;     N = 512;  nt = xb - 64; }
  else              { W = Wv; dst = Wt + (size_t)2560*2048;     N = 512;  nt = xb - 80; }
  const int n0 = nt*32, k0 = blockIdx.y*32;
  const int tx = threadIdx.x & 31, ty = threadIdx.x >> 5;
  #pragma unroll
  for (int i = 0; i < 4; ++i)
    tile[ty*4 + i][tx] = W[(size_t)(k0 + ty*4 + i)*N + n0 + tx];
  __syncthreads();
  #pragma unroll
  for (int i = 0; i < 4; ++i) {
    const int nl = ty*4 + i;
    dst[(size_t)(n0 + nl)*2048 + k0 + tx] = f2bf(tile[tx][nl]);
  }
}

// Single W transpose (for Wo)
__global__ __launch_bounds__(256) void transpose_f2b(
    const float* __restrict__ W, ushort_t* __restrict__ Wt, int K, int N)
{
  __shared__ float tile[32][33];
  const int n0 = blockIdx.x*32, k0 = blockIdx.y*32;
  const int tx = threadIdx.x & 31, ty = threadIdx.x >> 5;
  #pragma unroll
  for (int i = 0; i < 4; ++i)
    tile[ty*4 + i][tx] = W[(size_t)(k0 + ty*4 + i)*N + n0 + tx];
  __syncthreads();
  #pragma unroll
  for (int i = 0; i < 4; ++i) {
    const int nl = ty*4 + i;
    Wt[(size_t)(n0 + nl)*K + k0 + tx] = f2bf(tile[tx][nl]);
  }
}

// ---------------- bf16 MFMA GEMM v3: BM templated, 2 blocks/CU for TLP ----------
// BM=128 -> grid 512 = 2 blocks/CU, launch_bounds(512,4) caps VGPR at 128 so
// 4 waves/SIMD co-reside: co-resident blocks hide each other's stage-issue and
// end-of-tile drain stalls (the v11-attn lesson; 1-block/CU lockstep was ~50%
// stall). Same staging/swizzle/phase code as v2, parameters only.
template<int BM, int BN, int WN, bool B16OUT>
__global__ __launch_bounds__(512, 4) void bt_gemm3(
    const ushort_t* __restrict__ A, const ushort_t* __restrict__ Bt,
    void* __restrict__ Cv, int ldc)
{
  constexpr int WM = 8/WN;
  constexpr int MF = BM/WM/16;         // M-frags per wave
  constexpr int NF = BN/WN/16;         // N-frags per wave
  constexpr int AROUNDS = BM/64;       // A staging rounds (512 thr x 16B)
  constexpr int BROUNDS = BN/64;       // B staging rounds
  constexpr int BUFB = (BM + BN)*128;  // bytes per buffer
  __shared__ char smem[2*BUFB];

  const int t = threadIdx.x, lane = t & 63, w = t >> 6;
  const int wm = w / WN, wn = w % WN;
  const int bm = blockIdx.y*BM, bn = blockIdx.x*BN;
  const int lr = lane & 15, lg = lane >> 4;

  f32x4v acc[MF][NF];
  #pragma unroll
  for (int mf = 0; mf < MF; ++mf)
    #pragma unroll
    for (int nf = 0; nf < NF; ++nf)
      #pragma unroll
      for (int r = 0; r < 4; ++r) acc[mf][nf][r] = 0.f;

  const char* Ab = (const char*)A;
  const char* Bb = (const char*)Bt;

  auto stage = [&](int kt2, int d) {
    char* ab = smem + d*BUFB;
    char* bb = ab + BM*128;
    const int ktb = kt2*128;
    #pragma unroll
    for (int u = 0; u < AROUNDS; ++u) {
      const int idx = u*512 + t;
      const int row = idx >> 3;
      const int kb  = ((idx & 7)*16) ^ ((row & 7) << 4);
      gload16(Ab + (size_t)(bm + row)*4096 + ktb + kb, ab + idx*16);
    }
    #pragma unroll
    for (int u = 0; u < BROUNDS; ++u) {
      const int idx = u*512 + t;
      const int row = idx >> 3;
      const int kb  = ((idx & 7)*16) ^ ((row & 7) << 4);
      gload16(Bb + (size_t)(bn + row)*4096 + ktb + kb, bb + idx*16);
    }
  };

  stage(0, 0);
  __syncthreads();

#define PHASE(q) { \
    bf16x8 af0k0, af0k1, af1k0, af1k1; \
    { const int rm = wm*(MF*16) + (2*(q))*16 + lr; \
      const char* ap = asp + rm*128; \
      const int sw = (rm & 7) << 4; \
      af0k0 = *(const bf16x8*)(ap + ((lg*16) ^ sw)); \
      af0k1 = *(const bf16x8*)(ap + ((64 + lg*16) ^ sw)); } \
    { const int rm = wm*(MF*16) + (2*(q)+1)*16 + lr; \
      const char* ap = asp + rm*128; \
      const int sw = (rm & 7) << 4; \
      af1k0 = *(const bf16x8*)(ap + ((lg*16) ^ sw)); \
      af1k1 = *(const bf16x8*)(ap + ((64 + lg*16) ^ sw)); } \
    __builtin_amdgcn_s_setprio(1); \
    _Pragma("unroll") \
    for (int nf = 0; nf < NF; ++nf) { \
      acc[2*(q)][nf]   = __builtin_amdgcn_mfma_f32_16x16x32_bf16(af0k0, bfr[nf][0], acc[2*(q)][nf],   0,0,0); \
      acc[2*(q)][nf]   = __builtin_amdgcn_mfma_f32_16x16x32_bf16(af0k1, bfr[nf][1], acc[2*(q)][nf],   0,0,0); \
      acc[2*(q)+1][nf] = __builtin_amdgcn_mfma_f32_16x16x32_bf16(af1k0, bfr[nf][0], acc[2*(q)+1][nf], 0,0,0); \
      acc[2*(q)+1][nf] = __builtin_amdgcn_mfma_f32_16x16x32_bf16(af1k1, bfr[nf][1], acc[2*(q)+1][nf], 0,0,0); \
    } \
    __builtin_amdgcn_s_setprio(0); }

  int cur = 0;
  for (int kt = 0; kt < 32; ++kt) {
    if (kt < 31) stage(kt + 1, cur ^ 1);
    const char* asp = smem + cur*BUFB;
    const char* bsp = asp + BM*128;
    bf16x8 bfr[NF][2];
    #pragma unroll
    for (int nf = 0; nf < NF; ++nf) {
      const int rn = wn*(NF*16) + nf*16 + lr;
      const char* bp = bsp + rn*128;
      const int sw = (rn & 7) << 4;
      bfr[nf][0] = *(const bf16x8*)(bp + ((lg*16) ^ sw));
      bfr[nf][1] = *(const bf16x8*)(bp + ((64 + lg*16) ^ sw));
    }
    PHASE(0)
    if constexpr (MF >= 4) PHASE(1)
    if constexpr (MF >= 8) {
      PHASE(2)
      PHASE(3)
    }
    __syncthreads();
    cur ^= 1;
  }
#undef PHASE

  #pragma unroll
  for (int mf = 0; mf < MF; ++mf) {
    const int m = bm + wm*(MF*16) + mf*16 + lg*4;
    #pragma unroll
    for (int nf = 0; nf < NF; ++nf) {
      const int n = bn + wn*(NF*16) + nf*16 + lr;
      #pragma unroll
      for (int r = 0; r < 4; ++r) {
        if constexpr (B16OUT)
          ((ushort_t*)Cv)[(size_t)(m + r)*ldc + n] = f2bf(acc[mf][nf][r]);
        else
          ((float*)Cv)[(size_t)(m + r)*ldc + n] = acc[mf][nf][r];
      }
    }
  }
}

// RoPE on bf16 QKV; writes Qo (SM_SCALE*LOG2E folded) and Ko[b,hk][s][d].
__global__ __launch_bounds__(256) void rope_conv(
    const ushort_t* __restrict__ QKVb, ushort_t* __restrict__ Qo,
    ushort_t* __restrict__ Ko)
{
  const int total = NTOK * (NH + NKV) * (HD/2);
  int idx = blockIdx.x * 256 + threadIdx.x;
  if (idx >= total) return;
  const int i   = idx & 63;
  int tmp = idx >> 6;
  const int hs  = tmp % (NH + NKV);
  const int tkn = tmp / (NH + NKV);
  const int s   = tkn & (SEQ - 1);
  const int b   = tkn >> 11;
  const float invf = expf(-(float)i * 0.14391156831212787f);
  float sn, cs;
  sincosf((float)s * invf, &sn, &cs);
  const size_t base = (size_t)tkn * QKV_LD + (hs < NH ? hs * HD : KOFF + (hs - NH) * HD);
  const float x0 = bf2f(QKVb[base + i]);
  const float x1 = bf2f(QKVb[base + i + 64]);
  const float y0 = x0 * cs - x1 * sn;
  const float y1 = x1 * cs + x0 * sn;
  if (hs < NH) {
    ushort_t* q = Qo + (size_t)tkn * HIDDEN + hs * HD;
    q[i]      = f2bf(y0 * (SM_SCALE * LOG2E));
    q[i + 64] = f2bf(y1 * (SM_SCALE * LOG2E));
  } else {
    ushort_t* k = Ko + ((size_t)(b*NKV + (hs - NH))*SEQ + s) * HD;
    k[i]      = f2bf(y0);
    k[i + 64] = f2bf(y1);
  }
}

// V columns of QKVb -> Vtb[b,hk][d][s]
__global__ __launch_bounds__(256) void vt_conv(
    const ushort_t* __restrict__ QKVb, ushort_t* __restrict__ Vtb)
{
  __shared__ ushort_t tile[32][33];
  const int s0 = blockIdx.x*32;
  const int d0 = (blockIdx.y & 3)*32;
  const int bk = blockIdx.y >> 2;
  const int b = bk >> 2, hk = bk & 3;
  const int tx = threadIdx.x & 31, ty = threadIdx.x >> 5;
  #pragma unroll
  for (int i = 0; i < 4; ++i) {
    const int sl = ty*4 + i;
    tile[sl][tx] = QKVb[(size_t)(b*SEQ + s0 + sl)*QKV_LD + VOFF + hk*HD + d0 + tx];
  }
  __syncthreads();
  #pragma unroll
  for (int i = 0; i < 4; ++i) {
    const int dl = ty*4 + i;
    Vtb[((size_t)bk*HD + d0 + dl)*SEQ + s0 + tx] = tile[tx][dl];
  }
}

// ---------------- MFMA flash attention v11 (R14/R17 winner, exact) ----------
__global__ __launch_bounds__(256) void attn_mfma11(
    const ushort_t* __restrict__ Qb, const ushort_t* __restrict__ Kb,
    const ushort_t* __restrict__ Vtb, ushort_t* __restrict__ O)
{
  __shared__ char smem[65536];

  const int bx = blockIdx.x;                // b*NKV + hk
  const int qt = 63 - (int)blockIdx.y;      // big q-tiles dispatched first
  const int b = bx >> 2, hk = bx & 3;
  const int t = threadIdx.x, w = t >> 6, lane = t & 63;
  const int c = lane & 31, hi = lane >> 5;
  const int h = hk*4 + w;                   // this wave's q-head
  const int qw0 = qt*32;
  const int qg  = qw0 + c;
  const int nsteps = (qt + 2) >> 1;         // ceil((qt+1)/2) 64-key tiles

  const char* Kbb = (const char*)(Kb + (size_t)(b*NKV + hk)*SEQ*HD);
  const char* Vbb = (const char*)(Vtb + (size_t)(b*NKV + hk)*HD*SEQ);

  int ksrc[4], vsrc[4], ldst[4];
  #pragma unroll
  for (int u = 0; u < 4; ++u) {
    const int idx = u*256 + t;
    const int krow = idx >> 4, kof = (idx & 15) << 4;   // K: 64 rows x 256B
    ksrc[u] = krow*256 + (kof ^ ((krow & 15) << 4));
    const int vd = idx >> 3,  vof = (idx & 7) << 4;     // V: 128 dim-rows x 128B
    vsrc[u] = vd*(SEQ*2) + (vof ^ ((vd & 7) << 4));
    ldst[u] = idx*16;
  }

  bf16x8 qf[8];
  {
    const ushort_t* qrow = Qb + (size_t)(b*SEQ + qg)*HIDDEN + h*HD;
    #pragma unroll
    for (int kc = 0; kc < 8; ++kc)
      qf[kc] = *(const bf16x8*)(qrow + kc*16 + hi*8);
  }

  f32x16 ot[4];
  #pragma unroll
  for (int nc = 0; nc < 4; ++nc)
    #pragma unroll
    for (int r = 0; r < 16; ++r) ot[nc][r] = 0.f;
  float m = -1e30f, l = 0.f;

  #pragma unroll
  for (int u = 0; u < 4; ++u) {
    gload16(Kbb + ksrc[u], smem + ldst[u]);
    gload16(Vbb + vsrc[u], smem + 32768 + ldst[u]);
  }
  __syncthreads();

  int cur = 0;
  for (int kt = 0; kt < nsteps; ++kt) {
    if (kt + 1 < nsteps) {
      const int nb = cur ^ 1;
      const size_t kto = (size_t)(kt + 1) * 16384;
      const int    vto = (kt + 1) * 128;
      #pragma unroll
      for (int u = 0; u < 4; ++u) {
        gload16(Kbb + kto + ksrc[u], smem + nb*16384 + ldst[u]);
        gload16(Vbb + vto + vsrc[u], smem + 32768 + nb*16384 + ldst[u]);
      }
    }
    const char* klds = smem + cur*16384;
    const char* vlds = smem + 32768 + cur*16384;
    f32x16 s[2];
    #pragma unroll
    for (int kn = 0; kn < 2; ++kn)
      #pragma unroll
      for (int r = 0; r < 16; ++r) s[kn][r] = 0.f;
    #pragma unroll
    for (int kn = 0; kn < 2; ++kn) {
      const int row = kn*32 + c;
      const int sw = (row & 15) << 4;
      #pragma unroll
      for (int kc = 0; kc < 8; ++kc) {
        const bf16x8 ka = *(const bf16x8*)(klds + row*256 + ((kc*32 + hi*16) ^ sw));
        s[kn] = __builtin_amdgcn_mfma_f32_32x32x16_bf16(ka, qf[kc], s[kn], 0, 0, 0);
      }
    }
    if (kt == nsteps - 1) {
      #pragma unroll
      for (int kn = 0; kn < 2; ++kn)
        #pragma unroll
        for (int r = 0; r < 16; ++r) {
          const int kg_ = kt*64 + kn*32 + (r & 3) + 8*(r >> 2) + 4*hi;
          if (kg_ > qg) s[kn][r] = -1e30f;
        }
    }
    float mx[16];
    #pragma unroll
    for (int r = 0; r < 16; ++r) mx[r] = fmaxf(s[0][r], s[1][r]);
    #pragma unroll
    for (int st = 8; st > 0; st >>= 1)
      #pragma unroll
      for (int r = 0; r < 8; ++r)
        if (r < st) mx[r] = fmaxf(mx[r], mx[r + st]);
    const float pm = fmaxf(mx[0], __shfl_xor(mx[0], 32));
    if (!__all(pm - m <= 8.f)) {
      const float mnew = fmaxf(m, pm);
      const float corr = exp2f(m - mnew);
      m = mnew;
      l *= corr;
      #pragma unroll
      for (int nc = 0; nc < 4; ++nc) ot[nc] *= corr;
    }
    float ls = 0.f;
    #pragma unroll
    for (int kn = 0; kn < 2; ++kn)
      #pragma unroll
      for (int r = 0; r < 16; ++r) {
        const float p = exp2f(s[kn][r] - m);
        ls += p;
        s[kn][r] = p;
      }
    l += ls;
    #pragma unroll
    for (int kn = 0; kn < 2; ++kn) {
      #pragma unroll
      for (int rem = 0; rem < 2; ++rem) {
        const int base = 8*rem;
        const unsigned A0 = pack2(s[kn][base+0], s[kn][base+1]);
        const unsigned A1 = pack2(s[kn][base+2], s[kn][base+3]);
        const unsigned B0 = pack2(s[kn][base+4], s[kn][base+5]);
        const unsigned B1 = pack2(s[kn][base+6], s[kn][base+7]);
        const unsigned u  = hi ? A0 : B0;
        const unsigned v  = hi ? A1 : B1;
        const unsigned su = (unsigned)__shfl_xor((int)u, 32);
        const unsigned sv = (unsigned)__shfl_xor((int)v, 32);
        uint4 wv;
        wv.x = hi ? su : A0;
        wv.y = hi ? sv : A1;
        wv.z = hi ? B0 : su;
        wv.w = hi ? B1 : sv;
        const bf16x8 pb = __builtin_bit_cast(bf16x8, wv);
        const int kc = kn*2 + rem;
        #pragma unroll
        for (int nc = 0; nc < 4; ++nc) {
          const int dim = nc*32 + c;
          const bf16x8 va = *(const bf16x8*)(vlds + dim*128 + ((kc*32 + hi*16) ^ ((dim & 7) << 4)));
          ot[nc] = __builtin_amdgcn_mfma_f32_32x32x16_bf16(va, pb, ot[nc], 0, 0, 0);
        }
      }
    }
    __syncthreads();
    cur ^= 1;
  }

  const float lt = l + __shfl_xor(l, 32);
  const float inv = 1.f / lt;
  ushort_t* orow = O + (size_t)(b*SEQ + qg) * HIDDEN + h*HD;
  #pragma unroll
  for (int nc = 0; nc < 4; ++nc)
    #pragma unroll
    for (int r = 0; r < 16; r += 2) {
      const int dim = nc*32 + (r & 3) + 8*(r >> 2) + 4*hi;
      *(unsigned*)(orow + dim) = pack2(ot[nc][r]*inv, ot[nc][r+1]*inv);
    }
}

extern "C" void kernel_launch(void* const* d_in, const int* in_sizes, int n_in,
                              void* d_out, int out_size, void* d_ws, size_t ws_size,
                              hipStream_t stream)
{
  (void)in_sizes; (void)n_in; (void)out_size; (void)ws_size;
  const float* H  = (const float*)d_in[0];
  const float* Wq = (const float*)d_in[1];
  const float* Wk = (const float*)d_in[2];
  const float* Wv = (const float*)d_in[3];
  const float* Wo = (const float*)d_in[4];
  float* out = (float*)d_out;

  char* ws = (char*)d_ws;
  ushort_t* QKVb = (ushort_t*)ws;                      // [4096][3072] bf16  25.2 MB
  ushort_t* Hb   = (ushort_t*)(ws + 25165824);         // [4096][2048] bf16  (dead after gemm -> Qb)
  ushort_t* Qb   = Hb;
  ushort_t* Wt   = (ushort_t*)(ws + 41943040);         // [3072][2048] bf16  (reused for Wo)
  ushort_t* Kb   = (ushort_t*)(ws + 54525952);         // [2*4][2048][128]
  ushort_t* Vtb  = (ushort_t*)(ws + 58720256);         // [2*4][128][2048]
  ushort_t* Oat  = (ushort_t*)(ws + 62914560);         // [4096][2048] bf16

  conv_f2b<<<2048, 256, 0, stream>>>(H, Hb, NTOK*HIDDEN/16);
  transpose_qkv_f2b<<<dim3(96, 64), 256, 0, stream>>>(Wq, Wk, Wv, Wt);

  // BM=128 -> grid 16x32 = 512 blocks = 2/CU (TLP across blocks)
  bt_gemm3<128, 192, 4, true><<<dim3(16, 32), 512, 0, stream>>>(Hb, Wt, QKVb, QKV_LD);

  const int rope_total = NTOK * (NH + NKV) * (HD/2);
  rope_conv<<<(rope_total + 255)/256, 256, 0, stream>>>(QKVb, Qb, Kb);
  vt_conv<<<dim3(SEQ/32, 32), 256, 0, stream>>>(QKVb, Vtb);

  attn_mfma11<<<dim3(8, 64), 256, 0, stream>>>(Qb, Kb, Vtb, Oat);

  transpose_f2b<<<dim3(64, 64), 256, 0, stream>>>(Wo, Wt, 2048, 2048);
  bt_gemm3<128, 128, 2, false><<<dim3(16, 32), 512, 0, stream>>>(Oat, Wt, out, HIDDEN);
}

// Round 21
// 198.962 us; speedup vs baseline: 1.0454x; 1.0454x over previous
//
#include <hip/hip_runtime.h>
#include <hip/hip_bf16.h>
#include <cstdint>
#include <cstddef>

#define HIDDEN   2048
#define NH       16
#define NKV      4
#define HD       128
#define SEQ      2048
#define BATCH    2
#define NTOK     (BATCH*SEQ)      // 4096
#define QKV_LD   3072             // Q(2048) | K(512) | V(512)
#define KOFF     2048
#define VOFF     2560
#define SM_SCALE 0.08838834764831845f   // 1/sqrt(128)
#define LOG2E    1.4426950408889634f

typedef __attribute__((ext_vector_type(8)))  short bf16x8;
typedef __attribute__((ext_vector_type(4)))  float f32x4v;
typedef __attribute__((ext_vector_type(16))) float f32x16;
typedef unsigned short ushort_t;

__device__ __forceinline__ unsigned short f2bf(float f) {
  return __builtin_bit_cast(unsigned short, __float2bfloat16(f));
}
__device__ __forceinline__ float bf2f(ushort_t u) {
  return __builtin_bit_cast(float, (unsigned)u << 16);
}
__device__ __forceinline__ unsigned pack2(float a, float b) {
  return (unsigned)f2bf(a) | ((unsigned)f2bf(b) << 16);
}

// async global->LDS, 16B/lane; LDS dest lane-linear, swizzle realized on the GLOBAL src.
__device__ __forceinline__ void gload16(const void* g, void* l) {
  __builtin_amdgcn_global_load_lds(
      (const __attribute__((address_space(1))) unsigned int*)g,
      (__attribute__((address_space(3))) unsigned int*)l, 16, 0, 0);
}

// ---------------- prep: H->bf16 copy  fused with  Wq|Wk|Wv transpose ----------
// grid.x: [0,2048) conv blocks; [2048, 2048+6144) transpose blocks (96 x 64 tiles).
__global__ __launch_bounds__(256) void prep_fused(
    const float* __restrict__ H, ushort_t* __restrict__ Hb,
    const float* __restrict__ Wq, const float* __restrict__ Wk,
    const float* __restrict__ Wv, ushort_t* __restrict__ Wt)
{
  const int gb = blockIdx.x;
  if (gb < 2048) {
    // conv: 16 elems/thread (64B in / 32B out)
    const int i = gb*256 + threadIdx.x;
    const float4* ip = (const float4*)H + 4*i;
    const float4 a = ip[0], b = ip[1], c = ip[2], d = ip[3];
    uint4 r0, r1;
    r0.x = pack2(a.x, a.y); r0.y = pack2(a.z, a.w);
    r0.z = pack2(b.x, b.y); r0.w = pack2(b.z, b.w);
    r1.x = pack2(c.x, c.y); r1.y = pack2(c.z, c.w);
    r1.z = pack2(d.x, d.y); r1.w = pack2(d.z, d.w);
    ((uint4*)Hb)[2*i]   = r0;
    ((uint4*)Hb)[2*i+1] = r1;
    return;
  }
  __shared__ float tile[32][33];
  const int tb = gb - 2048;
  const int xb = tb % 96, yb = tb / 96;
  const float* W; ushort_t* dst; int N, nt;
  if (xb < 64)      { W = Wq; dst = Wt;                         N = 2048; nt = xb; }
  else if (xb < 80) { W = Wk; dst = Wt + (size_t)2048*2048;     N = 512;  nt = xb - 64; }
  else              { W = Wv; dst = Wt + (size_t)2560*2048;     N = 512;  nt = xb - 80; }
  const int n0 = nt*32, k0 = yb*32;
  const int tx = threadIdx.x & 31, ty = threadIdx.x >> 5;
  #pragma unroll
  for (int i = 0; i < 4; ++i)
    tile[ty*4 + i][tx] = W[(size_t)(k0 + ty*4 + i)*N + n0 + tx];
  __syncthreads();
  #pragma unroll
  for (int i = 0; i < 4; ++i) {
    const int nl = ty*4 + i;
    dst[(size_t)(n0 + nl)*2048 + k0 + tx] = f2bf(tile[tx][nl]);
  }
}

// Single W transpose (for Wo)
__global__ __launch_bounds__(256) void transpose_f2b(
    const float* __restrict__ W, ushort_t* __restrict__ Wt, int K, int N)
{
  __shared__ float tile[32][33];
  const int n0 = blockIdx.x*32, k0 = blockIdx.y*32;
  const int tx = threadIdx.x & 31, ty = threadIdx.x >> 5;
  #pragma unroll
  for (int i = 0; i < 4; ++i)
    tile[ty*4 + i][tx] = W[(size_t)(k0 + ty*4 + i)*N + n0 + tx];
  __syncthreads();
  #pragma unroll
  for (int i = 0; i < 4; ++i) {
    const int nl = ty*4 + i;
    Wt[(size_t)(n0 + nl)*K + k0 + tx] = f2bf(tile[tx][nl]);
  }
}

// ---------------- bf16 MFMA GEMM v2 (R19 exact): BM=256, 8 waves, dbuf issue-early ----
template<int BN, int WN, bool B16OUT>
__global__ __launch_bounds__(512, 1) void bt_gemm2(
    const ushort_t* __restrict__ A, const ushort_t* __restrict__ Bt,
    void* __restrict__ Cv, int ldc)
{
  constexpr int WM = 8/WN;
  constexpr int MF = 16/WM;
  constexpr int NF = BN/WN/16;
  constexpr int BROUNDS = BN/64;
  constexpr int BUFB = 32768 + BN*128;
  __shared__ char smem[2*BUFB];

  const int t = threadIdx.x, lane = t & 63, w = t >> 6;
  const int wm = w / WN, wn = w % WN;
  const int bm = blockIdx.y*256, bn = blockIdx.x*BN;
  const int lr = lane & 15, lg = lane >> 4;

  f32x4v acc[MF][NF];
  #pragma unroll
  for (int mf = 0; mf < MF; ++mf)
    #pragma unroll
    for (int nf = 0; nf < NF; ++nf)
      #pragma unroll
      for (int r = 0; r < 4; ++r) acc[mf][nf][r] = 0.f;

  const char* Ab = (const char*)A;
  const char* Bb = (const char*)Bt;

  auto stage = [&](int kt2, int d) {
    char* ab = smem + d*BUFB;
    char* bb = ab + 32768;
    const int ktb = kt2*128;
    #pragma unroll
    for (int u = 0; u < 4; ++u) {
      const int idx = u*512 + t;
      const int row = idx >> 3;
      const int kb  = ((idx & 7)*16) ^ ((row & 7) << 4);
      gload16(Ab + (size_t)(bm + row)*4096 + ktb + kb, ab + idx*16);
    }
    #pragma unroll
    for (int u = 0; u < BROUNDS; ++u) {
      const int idx = u*512 + t;
      const int row = idx >> 3;
      const int kb  = ((idx & 7)*16) ^ ((row & 7) << 4);
      gload16(Bb + (size_t)(bn + row)*4096 + ktb + kb, bb + idx*16);
    }
  };

  stage(0, 0);
  __syncthreads();

#define PHASE(q) { \
    bf16x8 af0k0, af0k1, af1k0, af1k1; \
    { const int rm = wm*(MF*16) + (2*(q))*16 + lr; \
      const char* ap = asp + rm*128; \
      const int sw = (rm & 7) << 4; \
      af0k0 = *(const bf16x8*)(ap + ((lg*16) ^ sw)); \
      af0k1 = *(const bf16x8*)(ap + ((64 + lg*16) ^ sw)); } \
    { const int rm = wm*(MF*16) + (2*(q)+1)*16 + lr; \
      const char* ap = asp + rm*128; \
      const int sw = (rm & 7) << 4; \
      af1k0 = *(const bf16x8*)(ap + ((lg*16) ^ sw)); \
      af1k1 = *(const bf16x8*)(ap + ((64 + lg*16) ^ sw)); } \
    __builtin_amdgcn_s_setprio(1); \
    _Pragma("unroll") \
    for (int nf = 0; nf < NF; ++nf) { \
      acc[2*(q)][nf]   = __builtin_amdgcn_mfma_f32_16x16x32_bf16(af0k0, bfr[nf][0], acc[2*(q)][nf],   0,0,0); \
      acc[2*(q)][nf]   = __builtin_amdgcn_mfma_f32_16x16x32_bf16(af0k1, bfr[nf][1], acc[2*(q)][nf],   0,0,0); \
      acc[2*(q)+1][nf] = __builtin_amdgcn_mfma_f32_16x16x32_bf16(af1k0, bfr[nf][0], acc[2*(q)+1][nf], 0,0,0); \
      acc[2*(q)+1][nf] = __builtin_amdgcn_mfma_f32_16x16x32_bf16(af1k1, bfr[nf][1], acc[2*(q)+1][nf], 0,0,0); \
    } \
    __builtin_amdgcn_s_setprio(0); }

  int cur = 0;
  for (int kt = 0; kt < 32; ++kt) {
    if (kt < 31) stage(kt + 1, cur ^ 1);
    const char* asp = smem + cur*BUFB;
    const char* bsp = asp + 32768;
    bf16x8 bfr[NF][2];
    #pragma unroll
    for (int nf = 0; nf < NF; ++nf) {
      const int rn = wn*(NF*16) + nf*16 + lr;
      const char* bp = bsp + rn*128;
      const int sw = (rn & 7) << 4;
      bfr[nf][0] = *(const bf16x8*)(bp + ((lg*16) ^ sw));
      bfr[nf][1] = *(const bf16x8*)(bp + ((64 + lg*16) ^ sw));
    }
    PHASE(0)
    PHASE(1)
    if constexpr (MF == 8) {
      PHASE(2)
      PHASE(3)
    }
    __syncthreads();
    cur ^= 1;
  }
#undef PHASE

  #pragma unroll
  for (int mf = 0; mf < MF; ++mf) {
    const int m = bm + wm*(MF*16) + mf*16 + lg*4;
    #pragma unroll
    for (int nf = 0; nf < NF; ++nf) {
      const int n = bn + wn*(NF*16) + nf*16 + lr;
      #pragma unroll
      for (int r = 0; r < 4; ++r) {
        if constexpr (B16OUT)
          ((ushort_t*)Cv)[(size_t)(m + r)*ldc + n] = f2bf(acc[mf][nf][r]);
        else
          ((float*)Cv)[(size_t)(m + r)*ldc + n] = acc[mf][nf][r];
      }
    }
  }
}

// ---------------- fused RoPE (Q + K) and V-transpose ------------------------
// grid.x: [0, RB) rope blocks; [RB, RB+2048) vt blocks (64 x 32 tiles).
#define ROPE_BLOCKS 20480   // NTOK*(NH+NKV)*(HD/2) / 256
__global__ __launch_bounds__(256) void ropevt_fused(
    const ushort_t* __restrict__ QKVb, ushort_t* __restrict__ Qo,
    ushort_t* __restrict__ Ko, ushort_t* __restrict__ Vtb)
{
  const int gb = blockIdx.x;
  if (gb < ROPE_BLOCKS) {
    const int idx = gb*256 + threadIdx.x;
    const int i   = idx & 63;
    int tmp = idx >> 6;
    const int hs  = tmp % (NH + NKV);
    const int tkn = tmp / (NH + NKV);
    const int s   = tkn & (SEQ - 1);
    const int b   = tkn >> 11;
    const float invf = expf(-(float)i * 0.14391156831212787f);
    float sn, cs;
    sincosf((float)s * invf, &sn, &cs);
    const size_t base = (size_t)tkn * QKV_LD + (hs < NH ? hs * HD : KOFF + (hs - NH) * HD);
    const float x0 = bf2f(QKVb[base + i]);
    const float x1 = bf2f(QKVb[base + i + 64]);
    const float y0 = x0 * cs - x1 * sn;
    const float y1 = x1 * cs + x0 * sn;
    if (hs < NH) {
      ushort_t* q = Qo + (size_t)tkn * HIDDEN + hs * HD;
      q[i]      = f2bf(y0 * (SM_SCALE * LOG2E));
      q[i + 64] = f2bf(y1 * (SM_SCALE * LOG2E));
    } else {
      ushort_t* k = Ko + ((size_t)(b*NKV + (hs - NH))*SEQ + s) * HD;
      k[i]      = f2bf(y0);
      k[i + 64] = f2bf(y1);
    }
    return;
  }
  __shared__ ushort_t tile[32][33];
  const int tb = gb - ROPE_BLOCKS;
  const int s0 = (tb & 63)*32;        // 64 s-tiles
  const int yb = tb >> 6;             // 32
  const int d0 = (yb & 3)*32;
  const int bk = yb >> 2;
  const int b = bk >> 2, hk = bk & 3;
  const int tx = threadIdx.x & 31, ty = threadIdx.x >> 5;
  #pragma unroll
  for (int i = 0; i < 4; ++i) {
    const int sl = ty*4 + i;
    tile[sl][tx] = QKVb[(size_t)(b*SEQ + s0 + sl)*QKV_LD + VOFF + hk*HD + d0 + tx];
  }
  __syncthreads();
  #pragma unroll
  for (int i = 0; i < 4; ++i) {
    const int dl = ty*4 + i;
    Vtb[((size_t)bk*HD + d0 + dl)*SEQ + s0 + tx] = tile[tx][dl];
  }
}

// ---------------- MFMA flash attention v11 (R14/R17/R19 winner, exact) ----------
__global__ __launch_bounds__(256) void attn_mfma11(
    const ushort_t* __restrict__ Qb, const ushort_t* __restrict__ Kb,
    const ushort_t* __restrict__ Vtb, ushort_t* __restrict__ O)
{
  __shared__ char smem[65536];

  const int bx = blockIdx.x;                // b*NKV + hk
  const int qt = 63 - (int)blockIdx.y;      // big q-tiles dispatched first
  const int b = bx >> 2, hk = bx & 3;
  const int t = threadIdx.x, w = t >> 6, lane = t & 63;
  const int c = lane & 31, hi = lane >> 5;
  const int h = hk*4 + w;                   // this wave's q-head
  const int qw0 = qt*32;
  const int qg  = qw0 + c;
  const int nsteps = (qt + 2) >> 1;         // ceil((qt+1)/2) 64-key tiles

  const char* Kbb = (const char*)(Kb + (size_t)(b*NKV + hk)*SEQ*HD);
  const char* Vbb = (const char*)(Vtb + (size_t)(b*NKV + hk)*HD*SEQ);

  int ksrc[4], vsrc[4], ldst[4];
  #pragma unroll
  for (int u = 0; u < 4; ++u) {
    const int idx = u*256 + t;
    const int krow = idx >> 4, kof = (idx & 15) << 4;   // K: 64 rows x 256B
    ksrc[u] = krow*256 + (kof ^ ((krow & 15) << 4));
    const int vd = idx >> 3,  vof = (idx & 7) << 4;     // V: 128 dim-rows x 128B
    vsrc[u] = vd*(SEQ*2) + (vof ^ ((vd & 7) << 4));
    ldst[u] = idx*16;
  }

  bf16x8 qf[8];
  {
    const ushort_t* qrow = Qb + (size_t)(b*SEQ + qg)*HIDDEN + h*HD;
    #pragma unroll
    for (int kc = 0; kc < 8; ++kc)
      qf[kc] = *(const bf16x8*)(qrow + kc*16 + hi*8);
  }

  f32x16 ot[4];
  #pragma unroll
  for (int nc = 0; nc < 4; ++nc)
    #pragma unroll
    for (int r = 0; r < 16; ++r) ot[nc][r] = 0.f;
  float m = -1e30f, l = 0.f;

  #pragma unroll
  for (int u = 0; u < 4; ++u) {
    gload16(Kbb + ksrc[u], smem + ldst[u]);
    gload16(Vbb + vsrc[u], smem + 32768 + ldst[u]);
  }
  __syncthreads();

  int cur = 0;
  for (int kt = 0; kt < nsteps; ++kt) {
    if (kt + 1 < nsteps) {
      const int nb = cur ^ 1;
      const size_t kto = (size_t)(kt + 1) * 16384;
      const int    vto = (kt + 1) * 128;
      #pragma unroll
      for (int u = 0; u < 4; ++u) {
        gload16(Kbb + kto + ksrc[u], smem + nb*16384 + ldst[u]);
        gload16(Vbb + vto + vsrc[u], smem + 32768 + nb*16384 + ldst[u]);
      }
    }
    const char* klds = smem + cur*16384;
    const char* vlds = smem + 32768 + cur*16384;
    f32x16 s[2];
    #pragma unroll
    for (int kn = 0; kn < 2; ++kn)
      #pragma unroll
      for (int r = 0; r < 16; ++r) s[kn][r] = 0.f;
    #pragma unroll
    for (int kn = 0; kn < 2; ++kn) {
      const int row = kn*32 + c;
      const int sw = (row & 15) << 4;
      #pragma unroll
      for (int kc = 0; kc < 8; ++kc) {
        const bf16x8 ka = *(const bf16x8*)(klds + row*256 + ((kc*32 + hi*16) ^ sw));
        s[kn] = __builtin_amdgcn_mfma_f32_32x32x16_bf16(ka, qf[kc], s[kn], 0, 0, 0);
      }
    }
    if (kt == nsteps - 1) {
      #pragma unroll
      for (int kn = 0; kn < 2; ++kn)
        #pragma unroll
        for (int r = 0; r < 16; ++r) {
          const int kg_ = kt*64 + kn*32 + (r & 3) + 8*(r >> 2) + 4*hi;
          if (kg_ > qg) s[kn][r] = -1e30f;
        }
    }
    float mx[16];
    #pragma unroll
    for (int r = 0; r < 16; ++r) mx[r] = fmaxf(s[0][r], s[1][r]);
    #pragma unroll
    for (int st = 8; st > 0; st >>= 1)
      #pragma unroll
      for (int r = 0; r < 8; ++r)
        if (r < st) mx[r] = fmaxf(mx[r], mx[r + st]);
    const float pm = fmaxf(mx[0], __shfl_xor(mx[0], 32));
    if (!__all(pm - m <= 8.f)) {
      const float mnew = fmaxf(m, pm);
      const float corr = exp2f(m - mnew);
      m = mnew;
      l *= corr;
      #pragma unroll
      for (int nc = 0; nc < 4; ++nc) ot[nc] *= corr;
    }
    float ls = 0.f;
    #pragma unroll
    for (int kn = 0; kn < 2; ++kn)
      #pragma unroll
      for (int r = 0; r < 16; ++r) {
        const float p = exp2f(s[kn][r] - m);
        ls += p;
        s[kn][r] = p;
      }
    l += ls;
    #pragma unroll
    for (int kn = 0; kn < 2; ++kn) {
      #pragma unroll
      for (int rem = 0; rem < 2; ++rem) {
        const int base = 8*rem;
        const unsigned A0 = pack2(s[kn][base+0], s[kn][base+1]);
        const unsigned A1 = pack2(s[kn][base+2], s[kn][base+3]);
        const unsigned B0 = pack2(s[kn][base+4], s[kn][base+5]);
        const unsigned B1 = pack2(s[kn][base+6], s[kn][base+7]);
        const unsigned u  = hi ? A0 : B0;
        const unsigned v  = hi ? A1 : B1;
        const unsigned su = (unsigned)__shfl_xor((int)u, 32);
        const unsigned sv = (unsigned)__shfl_xor((int)v, 32);
        uint4 wv;
        wv.x = hi ? su : A0;
        wv.y = hi ? sv : A1;
        wv.z = hi ? B0 : su;
        wv.w = hi ? B1 : sv;
        const bf16x8 pb = __builtin_bit_cast(bf16x8, wv);
        const int kc = kn*2 + rem;
        #pragma unroll
        for (int nc = 0; nc < 4; ++nc) {
          const int dim = nc*32 + c;
          const bf16x8 va = *(const bf16x8*)(vlds + dim*128 + ((kc*32 + hi*16) ^ ((dim & 7) << 4)));
          ot[nc] = __builtin_amdgcn_mfma_f32_32x32x16_bf16(va, pb, ot[nc], 0, 0, 0);
        }
      }
    }
    __syncthreads();
    cur ^= 1;
  }

  const float lt = l + __shfl_xor(l, 32);
  const float inv = 1.f / lt;
  ushort_t* orow = O + (size_t)(b*SEQ + qg) * HIDDEN + h*HD;
  #pragma unroll
  for (int nc = 0; nc < 4; ++nc)
    #pragma unroll
    for (int r = 0; r < 16; r += 2) {
      const int dim = nc*32 + (r & 3) + 8*(r >> 2) + 4*hi;
      *(unsigned*)(orow + dim) = pack2(ot[nc][r]*inv, ot[nc][r+1]*inv);
    }
}

extern "C" void kernel_launch(void* const* d_in, const int* in_sizes, int n_in,
                              void* d_out, int out_size, void* d_ws, size_t ws_size,
                              hipStream_t stream)
{
  (void)in_sizes; (void)n_in; (void)out_size; (void)ws_size;
  const float* H  = (const float*)d_in[0];
  const float* Wq = (const float*)d_in[1];
  const float* Wk = (const float*)d_in[2];
  const float* Wv = (const float*)d_in[3];
  const float* Wo = (const float*)d_in[4];
  float* out = (float*)d_out;

  char* ws = (char*)d_ws;
  ushort_t* QKVb = (ushort_t*)ws;                      // [4096][3072] bf16  25.2 MB
  ushort_t* Hb   = (ushort_t*)(ws + 25165824);         // [4096][2048] bf16  (dead after gemm -> Qb)
  ushort_t* Qb   = Hb;
  ushort_t* Wt   = (ushort_t*)(ws + 41943040);         // [3072][2048] bf16  (reused for Wo)
  ushort_t* Kb   = (ushort_t*)(ws + 54525952);         // [2*4][2048][128]
  ushort_t* Vtb  = (ushort_t*)(ws + 58720256);         // [2*4][128][2048]
  ushort_t* Oat  = (ushort_t*)(ws + 62914560);         // [4096][2048] bf16

  prep_fused<<<2048 + 96*64, 256, 0, stream>>>(H, Hb, Wq, Wk, Wv, Wt);

  // BN=192: grid 16x16 = 256 blocks = exactly 1/CU
  bt_gemm2<192, 4, true><<<dim3(16, 16), 512, 0, stream>>>(Hb, Wt, QKVb, QKV_LD);

  ropevt_fused<<<ROPE_BLOCKS + 2048, 256, 0, stream>>>(QKVb, Qb, Kb, Vtb);

  attn_mfma11<<<dim3(8, 64), 256, 0, stream>>>(Qb, Kb, Vtb, Oat);

  transpose_f2b<<<dim3(64, 64), 256, 0, stream>>>(Wo, Wt, 2048, 2048);
  bt_gemm2<128, 2, false><<<dim3(16, 16), 512, 0, stream>>>(Oat, Wt, out, HIDDEN);
}

// Round 22
// 198.528 us; speedup vs baseline: 1.0477x; 1.0022x over previous
//
#include <hip/hip_runtime.h>
#include <hip/hip_bf16.h>
#include <cstdint>
#include <cstddef>

#define HIDDEN   2048
#define NH       16
#define NKV      4
#define HD       128
#define SEQ      2048
#define BATCH    2
#define NTOK     (BATCH*SEQ)      // 4096
#define QKV_LD   3072             // Q(2048) | K(512) | V(512)
#define KOFF     2048
#define VOFF     2560
#define SM_SCALE 0.08838834764831845f   // 1/sqrt(128)
#define LOG2E    1.4426950408889634f

typedef __attribute__((ext_vector_type(8)))  short bf16x8;
typedef __attribute__((ext_vector_type(4)))  float f32x4v;
typedef __attribute__((ext_vector_type(16))) float f32x16;
typedef unsigned short ushort_t;

__device__ __forceinline__ unsigned short f2bf(float f) {
  return __builtin_bit_cast(unsigned short, __float2bfloat16(f));
}
__device__ __forceinline__ float bf2f(ushort_t u) {
  return __builtin_bit_cast(float, (unsigned)u << 16);
}
__device__ __forceinline__ unsigned pack2(float a, float b) {
  return (unsigned)f2bf(a) | ((unsigned)f2bf(b) << 16);
}

// async global->LDS, 16B/lane; LDS dest lane-linear, swizzle realized on the GLOBAL src.
__device__ __forceinline__ void gload16(const void* g, void* l) {
  __builtin_amdgcn_global_load_lds(
      (const __attribute__((address_space(1))) unsigned int*)g,
      (__attribute__((address_space(3))) unsigned int*)l, 16, 0, 0);
}

// ---------------- prep: H->bf16 copy  fused with  Wq|Wk|Wv transpose ----------
// grid.x: [0,2048) conv blocks; [2048, 2048+6144) transpose blocks (96 x 64 tiles).
__global__ __launch_bounds__(256) void prep_fused(
    const float* __restrict__ H, ushort_t* __restrict__ Hb,
    const float* __restrict__ Wq, const float* __restrict__ Wk,
    const float* __restrict__ Wv, ushort_t* __restrict__ Wt)
{
  const int gb = blockIdx.x;
  if (gb < 2048) {
    const int i = gb*256 + threadIdx.x;
    const float4* ip = (const float4*)H + 4*i;
    const float4 a = ip[0], b = ip[1], c = ip[2], d = ip[3];
    uint4 r0, r1;
    r0.x = pack2(a.x, a.y); r0.y = pack2(a.z, a.w);
    r0.z = pack2(b.x, b.y); r0.w = pack2(b.z, b.w);
    r1.x = pack2(c.x, c.y); r1.y = pack2(c.z, c.w);
    r1.z = pack2(d.x, d.y); r1.w = pack2(d.z, d.w);
    ((uint4*)Hb)[2*i]   = r0;
    ((uint4*)Hb)[2*i+1] = r1;
    return;
  }
  __shared__ float tile[32][33];
  const int tb = gb - 2048;
  const int xb = tb % 96, yb = tb / 96;
  const float* W; ushort_t* dst; int N, nt;
  if (xb < 64)      { W = Wq; dst = Wt;                         N = 2048; nt = xb; }
  else if (xb < 80) { W = Wk; dst = Wt + (size_t)2048*2048;     N = 512;  nt = xb - 64; }
  else              { W = Wv; dst = Wt + (size_t)2560*2048;     N = 512;  nt = xb - 80; }
  const int n0 = nt*32, k0 = yb*32;
  const int tx = threadIdx.x & 31, ty = threadIdx.x >> 5;
  #pragma unroll
  for (int i = 0; i < 4; ++i)
    tile[ty*4 + i][tx] = W[(size_t)(k0 + ty*4 + i)*N + n0 + tx];
  __syncthreads();
  #pragma unroll
  for (int i = 0; i < 4; ++i) {
    const int nl = ty*4 + i;
    dst[(size_t)(n0 + nl)*2048 + k0 + tx] = f2bf(tile[tx][nl]);
  }
}

// ---------------- bf16 MFMA GEMM v2 (R19 exact): BM=256, 8 waves, dbuf issue-early ----
template<int BN, int WN, bool B16OUT>
__global__ __launch_bounds__(512, 1) void bt_gemm2(
    const ushort_t* __restrict__ A, const ushort_t* __restrict__ Bt,
    void* __restrict__ Cv, int ldc)
{
  constexpr int WM = 8/WN;
  constexpr int MF = 16/WM;
  constexpr int NF = BN/WN/16;
  constexpr int BROUNDS = BN/64;
  constexpr int BUFB = 32768 + BN*128;
  __shared__ char smem[2*BUFB];

  const int t = threadIdx.x, lane = t & 63, w = t >> 6;
  const int wm = w / WN, wn = w % WN;
  const int bm = blockIdx.y*256, bn = blockIdx.x*BN;
  const int lr = lane & 15, lg = lane >> 4;

  f32x4v acc[MF][NF];
  #pragma unroll
  for (int mf = 0; mf < MF; ++mf)
    #pragma unroll
    for (int nf = 0; nf < NF; ++nf)
      #pragma unroll
      for (int r = 0; r < 4; ++r) acc[mf][nf][r] = 0.f;

  const char* Ab = (const char*)A;
  const char* Bb = (const char*)Bt;

  auto stage = [&](int kt2, int d) {
    char* ab = smem + d*BUFB;
    char* bb = ab + 32768;
    const int ktb = kt2*128;
    #pragma unroll
    for (int u = 0; u < 4; ++u) {
      const int idx = u*512 + t;
      const int row = idx >> 3;
      const int kb  = ((idx & 7)*16) ^ ((row & 7) << 4);
      gload16(Ab + (size_t)(bm + row)*4096 + ktb + kb, ab + idx*16);
    }
    #pragma unroll
    for (int u = 0; u < BROUNDS; ++u) {
      const int idx = u*512 + t;
      const int row = idx >> 3;
      const int kb  = ((idx & 7)*16) ^ ((row & 7) << 4);
      gload16(Bb + (size_t)(bn + row)*4096 + ktb + kb, bb + idx*16);
    }
  };

  stage(0, 0);
  __syncthreads();

#define PHASE(q) { \
    bf16x8 af0k0, af0k1, af1k0, af1k1; \
    { const int rm = wm*(MF*16) + (2*(q))*16 + lr; \
      const char* ap = asp + rm*128; \
      const int sw = (rm & 7) << 4; \
      af0k0 = *(const bf16x8*)(ap + ((lg*16) ^ sw)); \
      af0k1 = *(const bf16x8*)(ap + ((64 + lg*16) ^ sw)); } \
    { const int rm = wm*(MF*16) + (2*(q)+1)*16 + lr; \
      const char* ap = asp + rm*128; \
      const int sw = (rm & 7) << 4; \
      af1k0 = *(const bf16x8*)(ap + ((lg*16) ^ sw)); \
      af1k1 = *(const bf16x8*)(ap + ((64 + lg*16) ^ sw)); } \
    __builtin_amdgcn_s_setprio(1); \
    _Pragma("unroll") \
    for (int nf = 0; nf < NF; ++nf) { \
      acc[2*(q)][nf]   = __builtin_amdgcn_mfma_f32_16x16x32_bf16(af0k0, bfr[nf][0], acc[2*(q)][nf],   0,0,0); \
      acc[2*(q)][nf]   = __builtin_amdgcn_mfma_f32_16x16x32_bf16(af0k1, bfr[nf][1], acc[2*(q)][nf],   0,0,0); \
      acc[2*(q)+1][nf] = __builtin_amdgcn_mfma_f32_16x16x32_bf16(af1k0, bfr[nf][0], acc[2*(q)+1][nf], 0,0,0); \
      acc[2*(q)+1][nf] = __builtin_amdgcn_mfma_f32_16x16x32_bf16(af1k1, bfr[nf][1], acc[2*(q)+1][nf], 0,0,0); \
    } \
    __builtin_amdgcn_s_setprio(0); }

  int cur = 0;
  for (int kt = 0; kt < 32; ++kt) {
    if (kt < 31) stage(kt + 1, cur ^ 1);
    const char* asp = smem + cur*BUFB;
    const char* bsp = asp + 32768;
    bf16x8 bfr[NF][2];
    #pragma unroll
    for (int nf = 0; nf < NF; ++nf) {
      const int rn = wn*(NF*16) + nf*16 + lr;
      const char* bp = bsp + rn*128;
      const int sw = (rn & 7) << 4;
      bfr[nf][0] = *(const bf16x8*)(bp + ((lg*16) ^ sw));
      bfr[nf][1] = *(const bf16x8*)(bp + ((64 + lg*16) ^ sw));
    }
    PHASE(0)
    PHASE(1)
    if constexpr (MF == 8) {
      PHASE(2)
      PHASE(3)
    }
    __syncthreads();
    cur ^= 1;
  }
#undef PHASE

  #pragma unroll
  for (int mf = 0; mf < MF; ++mf) {
    const int m = bm + wm*(MF*16) + mf*16 + lg*4;
    #pragma unroll
    for (int nf = 0; nf < NF; ++nf) {
      const int n = bn + wn*(NF*16) + nf*16 + lr;
      #pragma unroll
      for (int r = 0; r < 4; ++r) {
        if constexpr (B16OUT)
          ((ushort_t*)Cv)[(size_t)(m + r)*ldc + n] = f2bf(acc[mf][nf][r]);
        else
          ((float*)Cv)[(size_t)(m + r)*ldc + n] = acc[mf][nf][r];
      }
    }
  }
}

// ---------------- fused RoPE (Q+K), V-transpose, and Wo-transpose --------------
// grid.x: [0, RB) rope | [RB, RB+2048) vt | [RB+2048, RB+2048+4096) Wo transpose.
// Wt is dead after qkv_gemm (stream-ordered before this kernel) -> safe to overwrite.
#define ROPE_BLOCKS 20480   // NTOK*(NH+NKV)*(HD/2) / 256
__global__ __launch_bounds__(256) void ropevt_fused(
    const ushort_t* __restrict__ QKVb, ushort_t* __restrict__ Qo,
    ushort_t* __restrict__ Ko, ushort_t* __restrict__ Vtb,
    const float* __restrict__ Wo, ushort_t* __restrict__ Wt)
{
  const int gb = blockIdx.x;
  if (gb < ROPE_BLOCKS) {
    const int idx = gb*256 + threadIdx.x;
    const int i   = idx & 63;
    int tmp = idx >> 6;
    const int hs  = tmp % (NH + NKV);
    const int tkn = tmp / (NH + NKV);
    const int s   = tkn & (SEQ - 1);
    const int b   = tkn >> 11;
    const float invf = expf(-(float)i * 0.14391156831212787f);
    float sn, cs;
    sincosf((float)s * invf, &sn, &cs);
    const size_t base = (size_t)tkn * QKV_LD + (hs < NH ? hs * HD : KOFF + (hs - NH) * HD);
    const float x0 = bf2f(QKVb[base + i]);
    const float x1 = bf2f(QKVb[base + i + 64]);
    const float y0 = x0 * cs - x1 * sn;
    const float y1 = x1 * cs + x0 * sn;
    if (hs < NH) {
      ushort_t* q = Qo + (size_t)tkn * HIDDEN + hs * HD;
      q[i]      = f2bf(y0 * (SM_SCALE * LOG2E));
      q[i + 64] = f2bf(y1 * (SM_SCALE * LOG2E));
    } else {
      ushort_t* k = Ko + ((size_t)(b*NKV + (hs - NH))*SEQ + s) * HD;
      k[i]      = f2bf(y0);
      k[i + 64] = f2bf(y1);
    }
    return;
  }
  __shared__ ushort_t tileu[32][33];
  if (gb < ROPE_BLOCKS + 2048) {
    const int tb = gb - ROPE_BLOCKS;
    const int s0 = (tb & 63)*32;
    const int yb = tb >> 6;
    const int d0 = (yb & 3)*32;
    const int bk = yb >> 2;
    const int b = bk >> 2, hk = bk & 3;
    const int tx = threadIdx.x & 31, ty = threadIdx.x >> 5;
    #pragma unroll
    for (int i = 0; i < 4; ++i) {
      const int sl = ty*4 + i;
      tileu[sl][tx] = QKVb[(size_t)(b*SEQ + s0 + sl)*QKV_LD + VOFF + hk*HD + d0 + tx];
    }
    __syncthreads();
    #pragma unroll
    for (int i = 0; i < 4; ++i) {
      const int dl = ty*4 + i;
      Vtb[((size_t)bk*HD + d0 + dl)*SEQ + s0 + tx] = tileu[tx][dl];
    }
    return;
  }
  // Wo transpose: W[2048][2048] fp32 -> Wt[2048][2048] bf16 (64 x 64 tiles)
  {
    float (*tf)[33] = (float(*)[33])&tileu[0][0];   // reuse LDS (only 32x33 floats needed)
    __shared__ float tile2[32][33];
    const int tb = gb - ROPE_BLOCKS - 2048;
    const int n0 = (tb & 63)*32, k0 = (tb >> 6)*32;
    const int tx = threadIdx.x & 31, ty = threadIdx.x >> 5;
    (void)tf;
    #pragma unroll
    for (int i = 0; i < 4; ++i)
      tile2[ty*4 + i][tx] = Wo[(size_t)(k0 + ty*4 + i)*2048 + n0 + tx];
    __syncthreads();
    #pragma unroll
    for (int i = 0; i < 4; ++i) {
      const int nl = ty*4 + i;
      Wt[(size_t)(n0 + nl)*2048 + k0 + tx] = f2bf(tile2[tx][nl]);
    }
  }
}

// ---------------- MFMA flash attention v11 (R14/R17/R19 winner, exact) ----------
__global__ __launch_bounds__(256) void attn_mfma11(
    const ushort_t* __restrict__ Qb, const ushort_t* __restrict__ Kb,
    const ushort_t* __restrict__ Vtb, ushort_t* __restrict__ O)
{
  __shared__ char smem[65536];

  const int bx = blockIdx.x;                // b*NKV + hk
  const int qt = 63 - (int)blockIdx.y;      // big q-tiles dispatched first
  const int b = bx >> 2, hk = bx & 3;
  const int t = threadIdx.x, w = t >> 6, lane = t & 63;
  const int c = lane & 31, hi = lane >> 5;
  const int h = hk*4 + w;                   // this wave's q-head
  const int qw0 = qt*32;
  const int qg  = qw0 + c;
  const int nsteps = (qt + 2) >> 1;         // ceil((qt+1)/2) 64-key tiles

  const char* Kbb = (const char*)(Kb + (size_t)(b*NKV + hk)*SEQ*HD);
  const char* Vbb = (const char*)(Vtb + (size_t)(b*NKV + hk)*HD*SEQ);

  int ksrc[4], vsrc[4], ldst[4];
  #pragma unroll
  for (int u = 0; u < 4; ++u) {
    const int idx = u*256 + t;
    const int krow = idx >> 4, kof = (idx & 15) << 4;   // K: 64 rows x 256B
    ksrc[u] = krow*256 + (kof ^ ((krow & 15) << 4));
    const int vd = idx >> 3,  vof = (idx & 7) << 4;     // V: 128 dim-rows x 128B
    vsrc[u] = vd*(SEQ*2) + (vof ^ ((vd & 7) << 4));
    ldst[u] = idx*16;
  }

  bf16x8 qf[8];
  {
    const ushort_t* qrow = Qb + (size_t)(b*SEQ + qg)*HIDDEN + h*HD;
    #pragma unroll
    for (int kc = 0; kc < 8; ++kc)
      qf[kc] = *(const bf16x8*)(qrow + kc*16 + hi*8);
  }

  f32x16 ot[4];
  #pragma unroll
  for (int nc = 0; nc < 4; ++nc)
    #pragma unroll
    for (int r = 0; r < 16; ++r) ot[nc][r] = 0.f;
  float m = -1e30f, l = 0.f;

  #pragma unroll
  for (int u = 0; u < 4; ++u) {
    gload16(Kbb + ksrc[u], smem + ldst[u]);
    gload16(Vbb + vsrc[u], smem + 32768 + ldst[u]);
  }
  __syncthreads();

  int cur = 0;
  for (int kt = 0; kt < nsteps; ++kt) {
    if (kt + 1 < nsteps) {
      const int nb = cur ^ 1;
      const size_t kto = (size_t)(kt + 1) * 16384;
      const int    vto = (kt + 1) * 128;
      #pragma unroll
      for (int u = 0; u < 4; ++u) {
        gload16(Kbb + kto + ksrc[u], smem + nb*16384 + ldst[u]);
        gload16(Vbb + vto + vsrc[u], smem + 32768 + nb*16384 + ldst[u]);
      }
    }
    const char* klds = smem + cur*16384;
    const char* vlds = smem + 32768 + cur*16384;
    f32x16 s[2];
    #pragma unroll
    for (int kn = 0; kn < 2; ++kn)
      #pragma unroll
      for (int r = 0; r < 16; ++r) s[kn][r] = 0.f;
    #pragma unroll
    for (int kn = 0; kn < 2; ++kn) {
      const int row = kn*32 + c;
      const int sw = (row & 15) << 4;
      #pragma unroll
      for (int kc = 0; kc < 8; ++kc) {
        const bf16x8 ka = *(const bf16x8*)(klds + row*256 + ((kc*32 + hi*16) ^ sw));
        s[kn] = __builtin_amdgcn_mfma_f32_32x32x16_bf16(ka, qf[kc], s[kn], 0, 0, 0);
      }
    }
    if (kt == nsteps - 1) {
      #pragma unroll
      for (int kn = 0; kn < 2; ++kn)
        #pragma unroll
        for (int r = 0; r < 16; ++r) {
          const int kg_ = kt*64 + kn*32 + (r & 3) + 8*(r >> 2) + 4*hi;
          if (kg_ > qg) s[kn][r] = -1e30f;
        }
    }
    float mx[16];
    #pragma unroll
    for (int r = 0; r < 16; ++r) mx[r] = fmaxf(s[0][r], s[1][r]);
    #pragma unroll
    for (int st = 8; st > 0; st >>= 1)
      #pragma unroll
      for (int r = 0; r < 8; ++r)
        if (r < st) mx[r] = fmaxf(mx[r], mx[r + st]);
    const float pm = fmaxf(mx[0], __shfl_xor(mx[0], 32));
    if (!__all(pm - m <= 8.f)) {
      const float mnew = fmaxf(m, pm);
      const float corr = exp2f(m - mnew);
      m = mnew;
      l *= corr;
      #pragma unroll
      for (int nc = 0; nc < 4; ++nc) ot[nc] *= corr;
    }
    float ls = 0.f;
    #pragma unroll
    for (int kn = 0; kn < 2; ++kn)
      #pragma unroll
      for (int r = 0; r < 16; ++r) {
        const float p = exp2f(s[kn][r] - m);
        ls += p;
        s[kn][r] = p;
      }
    l += ls;
    #pragma unroll
    for (int kn = 0; kn < 2; ++kn) {
      #pragma unroll
      for (int rem = 0; rem < 2; ++rem) {
        const int base = 8*rem;
        const unsigned A0 = pack2(s[kn][base+0], s[kn][base+1]);
        const unsigned A1 = pack2(s[kn][base+2], s[kn][base+3]);
        const unsigned B0 = pack2(s[kn][base+4], s[kn][base+5]);
        const unsigned B1 = pack2(s[kn][base+6], s[kn][base+7]);
        const unsigned u  = hi ? A0 : B0;
        const unsigned v  = hi ? A1 : B1;
        const unsigned su = (unsigned)__shfl_xor((int)u, 32);
        const unsigned sv = (unsigned)__shfl_xor((int)v, 32);
        uint4 wv;
        wv.x = hi ? su : A0;
        wv.y = hi ? sv : A1;
        wv.z = hi ? B0 : su;
        wv.w = hi ? B1 : sv;
        const bf16x8 pb = __builtin_bit_cast(bf16x8, wv);
        const int kc = kn*2 + rem;
        #pragma unroll
        for (int nc = 0; nc < 4; ++nc) {
          const int dim = nc*32 + c;
          const bf16x8 va = *(const bf16x8*)(vlds + dim*128 + ((kc*32 + hi*16) ^ ((dim & 7) << 4)));
          ot[nc] = __builtin_amdgcn_mfma_f32_32x32x16_bf16(va, pb, ot[nc], 0, 0, 0);
        }
      }
    }
    __syncthreads();
    cur ^= 1;
  }

  const float lt = l + __shfl_xor(l, 32);
  const float inv = 1.f / lt;
  ushort_t* orow = O + (size_t)(b*SEQ + qg) * HIDDEN + h*HD;
  #pragma unroll
  for (int nc = 0; nc < 4; ++nc)
    #pragma unroll
    for (int r = 0; r < 16; r += 2) {
      const int dim = nc*32 + (r & 3) + 8*(r >> 2) + 4*hi;
      *(unsigned*)(orow + dim) = pack2(ot[nc][r]*inv, ot[nc][r+1]*inv);
    }
}

extern "C" void kernel_launch(void* const* d_in, const int* in_sizes, int n_in,
                              void* d_out, int out_size, void* d_ws, size_t ws_size,
                              hipStream_t stream)
{
  (void)in_sizes; (void)n_in; (void)out_size; (void)ws_size;
  const float* H  = (const float*)d_in[0];
  const float* Wq = (const float*)d_in[1];
  const float* Wk = (const float*)d_in[2];
  const float* Wv = (const float*)d_in[3];
  const float* Wo = (const float*)d_in[4];
  float* out = (float*)d_out;

  char* ws = (char*)d_ws;
  ushort_t* QKVb = (ushort_t*)ws;                      // [4096][3072] bf16  25.2 MB
  ushort_t* Hb   = (ushort_t*)(ws + 25165824);         // [4096][2048] bf16  (dead after gemm -> Qb)
  ushort_t* Qb   = Hb;
  ushort_t* Wt   = (ushort_t*)(ws + 41943040);         // [3072][2048] bf16  (reused for Wo)
  ushort_t* Kb   = (ushort_t*)(ws + 54525952);         // [2*4][2048][128]
  ushort_t* Vtb  = (ushort_t*)(ws + 58720256);         // [2*4][128][2048]
  ushort_t* Oat  = (ushort_t*)(ws + 62914560);         // [4096][2048] bf16

  prep_fused<<<2048 + 96*64, 256, 0, stream>>>(H, Hb, Wq, Wk, Wv, Wt);

  // BN=192: grid 16x16 = 256 blocks = exactly 1/CU
  bt_gemm2<192, 4, true><<<dim3(16, 16), 512, 0, stream>>>(Hb, Wt, QKVb, QKV_LD);

  // rope + vt + Wo-transpose (Wt dead after qkv_gemm -> safe overwrite)
  ropevt_fused<<<ROPE_BLOCKS + 2048 + 4096, 256, 0, stream>>>(QKVb, Qb, Kb, Vtb, Wo, Wt);

  attn_mfma11<<<dim3(8, 64), 256, 0, stream>>>(Qb, Kb, Vtb, Oat);

  bt_gemm2<128, 2, false><<<dim3(16, 16), 512, 0, stream>>>(Oat, Wt, out, HIDDEN);
}